// Round 2
// baseline (526.121 us; speedup 1.0000x reference)
//
#include <hip/hip_runtime.h>

// SPADELight: x[8,128,256,256] f32, segmap[8,20,256,256] f32,
// weight[20,128] f32, bias[20,128] f32 -> out[8,128,256,256] f32.
constexpr int N_ = 8;
constexpr int C_ = 128;
constexpr int H_ = 256;
constexpr int W_ = 256;
constexpr int L_ = 20;
constexpr int HW = H_ * W_;            // 65536
constexpr float EPS = 1e-5f;

constexpr int STAT_CH  = 4;                    // stats chunks per (n,c)
constexpr int STAT_BLOCKS = N_ * C_ * STAT_CH; // 4096
constexpr int AMAX_BLOCKS = N_ * HW / 2 / 256; // 1024 (2 px/thread)
constexpr int CHUNK_PX = HW / STAT_CH;         // 16384 px per stats block

// ---------------------------------------------------------------------------
// Pass 1 (fused): blocks [0, STAT_BLOCKS) compute per-(n,c,chunk) partial
// sum/sumsq; blocks [STAT_BLOCKS, +AMAX_BLOCKS) compute per-pixel argmax of
// segmap. Fusing keeps 8 blocks/CU resident and both HBM streams in flight.
// ---------------------------------------------------------------------------
__global__ __launch_bounds__(256) void spade_pass1(const float* __restrict__ x,
                                                   const float* __restrict__ seg,
                                                   float* __restrict__ partials,
                                                   unsigned char* __restrict__ cls) {
    const int b = blockIdx.x;
    if (b < STAT_BLOCKS) {
        // ---- stats partials: 16384 px = 4096 float4, 16 per thread ----
        const int nc = b >> 2;
        const int ch = b & 3;
        const float4* xp = reinterpret_cast<const float4*>(
            x + (size_t)nc * HW + (size_t)ch * CHUNK_PX);

        float s = 0.f, s2 = 0.f;
        #pragma unroll 4
        for (int i = threadIdx.x; i < CHUNK_PX / 4; i += 256) {  // 16 iters
            float4 v = xp[i];
            s  += v.x + v.y + v.z + v.w;
            s2 += v.x * v.x + v.y * v.y + v.z * v.z + v.w * v.w;
        }
        #pragma unroll
        for (int off = 32; off > 0; off >>= 1) {
            s  += __shfl_down(s, off, 64);
            s2 += __shfl_down(s2, off, 64);
        }
        __shared__ float ls[4], ls2[4];
        const int wid = threadIdx.x >> 6;
        if ((threadIdx.x & 63) == 0) { ls[wid] = s; ls2[wid] = s2; }
        __syncthreads();
        if (threadIdx.x == 0) {
            partials[2 * b]     = ls[0] + ls[1] + ls[2] + ls[3];
            partials[2 * b + 1] = ls2[0] + ls2[1] + ls2[2] + ls2[3];
        }
    } else {
        // ---- argmax: 2 consecutive pixels per thread (float2 per class) ----
        const int t = (b - STAT_BLOCKS) * 256 + threadIdx.x;
        const int per_n = HW / 2;                 // 32768 threads per image
        const int n  = t / per_n;
        const int p2 = (t - n * per_n) * 2;

        const float* base = seg + (size_t)n * L_ * HW + p2;
        float2 best = *reinterpret_cast<const float2*>(base);
        uchar2 bi = {0, 0};
        #pragma unroll
        for (int l = 1; l < L_; ++l) {
            float2 v = *reinterpret_cast<const float2*>(base + (size_t)l * HW);
            if (v.x > best.x) { best.x = v.x; bi.x = (unsigned char)l; }  // strict >
            if (v.y > best.y) { best.y = v.y; bi.y = (unsigned char)l; }  // = first-max
        }
        *reinterpret_cast<uchar2*>(cls + (size_t)n * HW + p2) = bi;
    }
}

// ---------------------------------------------------------------------------
// Pass 2: out = fmaf(x, scale[cls], shift[cls]); finalize of mean/inv fused
// (8 L2-hit scalar loads per block). 8 blocks per (n,c) x 8192 px each.
// ---------------------------------------------------------------------------
__global__ __launch_bounds__(256) void spade_apply(const float* __restrict__ x,
                                                   const float* __restrict__ weight,
                                                   const float* __restrict__ bias,
                                                   const float* __restrict__ partials,
                                                   const unsigned char* __restrict__ cls,
                                                   float* __restrict__ out) {
    const int bid   = blockIdx.x;
    const int nc    = bid >> 3;
    const int chunk = bid & 7;
    const int n = nc >> 7;           // C_=128
    const int c = nc & (C_ - 1);

    __shared__ float s_scale[L_], s_shift[L_];
    if (threadIdx.x < L_) {
        const float* p = partials + 8 * nc;      // 4 chunks x {sum, sumsq}
        float ts  = p[0] + p[2] + p[4] + p[6];
        float ts2 = p[1] + p[3] + p[5] + p[7];
        float mean = ts / (float)HW;
        float var  = ts2 / (float)HW - mean * mean;   // biased var (ref)
        float inv  = rsqrtf(var + EPS);
        const int l = threadIdx.x;
        float sc = inv * weight[l * C_ + c];
        s_scale[l] = sc;
        s_shift[l] = bias[l * C_ + c] - mean * sc;
    }
    __syncthreads();

    const size_t base = (size_t)nc * HW + (size_t)chunk * 8192;
    const float4* xp = reinterpret_cast<const float4*>(x + base);
    float4*       op = reinterpret_cast<float4*>(out + base);
    const uchar4* cp = reinterpret_cast<const uchar4*>(cls + (size_t)n * HW + chunk * 8192);

    #pragma unroll
    for (int i = 0; i < 8; ++i) {
        const int idx = i * 256 + threadIdx.x;
        float4 v  = xp[idx];
        uchar4 cc = cp[idx];
        float4 r;
        r.x = fmaf(v.x, s_scale[cc.x], s_shift[cc.x]);
        r.y = fmaf(v.y, s_scale[cc.y], s_shift[cc.y]);
        r.z = fmaf(v.z, s_scale[cc.z], s_shift[cc.z]);
        r.w = fmaf(v.w, s_scale[cc.w], s_shift[cc.w]);
        op[idx] = r;
    }
}

// ---------------------------------------------------------------------------
extern "C" void kernel_launch(void* const* d_in, const int* in_sizes, int n_in,
                              void* d_out, int out_size, void* d_ws, size_t ws_size,
                              hipStream_t stream) {
    const float* x      = (const float*)d_in[0];
    const float* segmap = (const float*)d_in[1];
    const float* weight = (const float*)d_in[2];
    const float* bias   = (const float*)d_in[3];
    float* out = (float*)d_out;

    // ws layout: partials[4096*2] f32 (32 KB) | cls bytes (512 KB)
    float* partials = (float*)d_ws;
    unsigned char* cls = (unsigned char*)d_ws + 32768;

    spade_pass1<<<STAT_BLOCKS + AMAX_BLOCKS, 256, 0, stream>>>(x, segmap, partials, cls);
    spade_apply<<<N_ * C_ * 8, 256, 0, stream>>>(x, weight, bias, partials, cls, out);
}

// Round 3
// 510.547 us; speedup vs baseline: 1.0305x; 1.0305x over previous
//
#include <hip/hip_runtime.h>

// SPADELight: x[8,128,256,256] f32, segmap[8,20,256,256] f32,
// weight[20,128] f32, bias[20,128] f32 -> out[8,128,256,256] f32.
//
// Structure: per-image software pipeline over 9 launches.
//   launch k (k=0..8): apply(image k-1)  ||  stats+argmax(image k)
// The apply re-read of x[k-1] (33.5 MB) hits L3 (streamed by launch k-1),
// removing ~268 MB of HBM fetch vs the monolithic 2-pass version.
constexpr int N_ = 8;
constexpr int C_ = 128;
constexpr int H_ = 256;
constexpr int W_ = 256;
constexpr int L_ = 20;
constexpr int HW = H_ * W_;            // 65536
constexpr float EPS = 1e-5f;

constexpr int STAT_CH = 4;                            // stats chunks per (c)
constexpr int PX_PER_STAT = HW / STAT_CH;             // 16384 px
constexpr int STATS_BLOCKS_PER_IMG = C_ * STAT_CH;    // 512
constexpr int AMAX_BLOCKS_PER_IMG  = HW / 2 / 256;    // 128 (2 px/thread)
constexpr int APPLY_CH = 8;                           // apply chunks per (c)
constexpr int APPLY_PX = HW / APPLY_CH;               // 8192 px
constexpr int APPLY_BLOCKS_PER_IMG = C_ * APPLY_CH;   // 1024

// Block roles within one fused launch:
//   [0, napply)                 : apply image (apply_img)
//   [napply, napply+nstats)     : stats partials image (stats_img)
//   [napply+nstats, end)        : argmax image (stats_img)
__global__ __launch_bounds__(256) void spade_fused(
    const float* __restrict__ x, const float* __restrict__ seg,
    const float* __restrict__ weight, const float* __restrict__ bias,
    float* __restrict__ partials, unsigned char* __restrict__ cls,
    float* __restrict__ out, int apply_img, int stats_img,
    int napply, int nstats)
{
    const int b = blockIdx.x;

    if (b < napply) {
        // ---------------- apply: out = fma(x, scale[cls], shift[cls]) -----
        const int c     = b >> 3;
        const int chunk = b & 7;
        const int nc    = apply_img * C_ + c;

        __shared__ float s_scale[L_], s_shift[L_];
        if (threadIdx.x < L_) {
            const float* p = partials + 8 * nc;       // 4 chunks x {sum,sumsq}
            float ts   = p[0] + p[2] + p[4] + p[6];
            float ts2  = p[1] + p[3] + p[5] + p[7];
            float mean = ts / (float)HW;
            float var  = ts2 / (float)HW - mean * mean;   // biased var (ref)
            float inv  = rsqrtf(var + EPS);
            const int l = threadIdx.x;
            float sc = inv * weight[l * C_ + c];
            s_scale[l] = sc;
            s_shift[l] = bias[l * C_ + c] - mean * sc;
        }
        __syncthreads();

        const size_t base = (size_t)nc * HW + (size_t)chunk * APPLY_PX;
        const float4* xp = reinterpret_cast<const float4*>(x + base);
        float4*       op = reinterpret_cast<float4*>(out + base);
        const uchar4* cp = reinterpret_cast<const uchar4*>(
            cls + (size_t)apply_img * HW + chunk * APPLY_PX);

        #pragma unroll
        for (int i = 0; i < APPLY_PX / 4 / 256; ++i) {   // 8 iters
            const int idx = i * 256 + threadIdx.x;
            float4 v  = xp[idx];
            uchar4 cc = cp[idx];
            float4 r;
            r.x = fmaf(v.x, s_scale[cc.x], s_shift[cc.x]);
            r.y = fmaf(v.y, s_scale[cc.y], s_shift[cc.y]);
            r.z = fmaf(v.z, s_scale[cc.z], s_shift[cc.z]);
            r.w = fmaf(v.w, s_scale[cc.w], s_shift[cc.w]);
            op[idx] = r;
        }
    } else if (b < napply + nstats) {
        // ---------------- stats partials: sum / sumsq over 16384 px -------
        const int b2 = b - napply;
        const int c  = b2 >> 2;
        const int ch = b2 & 3;
        const int nc = stats_img * C_ + c;
        const float4* xp = reinterpret_cast<const float4*>(
            x + (size_t)nc * HW + (size_t)ch * PX_PER_STAT);

        float s = 0.f, s2 = 0.f;
        #pragma unroll 4
        for (int i = threadIdx.x; i < PX_PER_STAT / 4; i += 256) {  // 16 iters
            float4 v = xp[i];
            s  += v.x + v.y + v.z + v.w;
            s2 += v.x * v.x + v.y * v.y + v.z * v.z + v.w * v.w;
        }
        #pragma unroll
        for (int off = 32; off > 0; off >>= 1) {
            s  += __shfl_down(s, off, 64);
            s2 += __shfl_down(s2, off, 64);
        }
        __shared__ float ls[4], ls2[4];
        const int wid = threadIdx.x >> 6;
        if ((threadIdx.x & 63) == 0) { ls[wid] = s; ls2[wid] = s2; }
        __syncthreads();
        if (threadIdx.x == 0) {
            partials[8 * nc + 2 * ch]     = ls[0] + ls[1] + ls[2] + ls[3];
            partials[8 * nc + 2 * ch + 1] = ls2[0] + ls2[1] + ls2[2] + ls2[3];
        }
    } else {
        // ---------------- argmax: 2 px/thread over L=20 classes ----------
        const int b3 = b - napply - nstats;
        const int t  = b3 * 256 + threadIdx.x;        // 0..32767
        const int p2 = t * 2;

        const float* base = seg + (size_t)stats_img * L_ * HW + p2;
        float2 best = *reinterpret_cast<const float2*>(base);
        uchar2 bi = {0, 0};
        #pragma unroll
        for (int l = 1; l < L_; ++l) {
            float2 v = *reinterpret_cast<const float2*>(base + (size_t)l * HW);
            if (v.x > best.x) { best.x = v.x; bi.x = (unsigned char)l; }  // strict >
            if (v.y > best.y) { best.y = v.y; bi.y = (unsigned char)l; }  // = first-max
        }
        *reinterpret_cast<uchar2*>(cls + (size_t)stats_img * HW + p2) = bi;
    }
}

// ---------------------------------------------------------------------------
extern "C" void kernel_launch(void* const* d_in, const int* in_sizes, int n_in,
                              void* d_out, int out_size, void* d_ws, size_t ws_size,
                              hipStream_t stream) {
    const float* x      = (const float*)d_in[0];
    const float* segmap = (const float*)d_in[1];
    const float* weight = (const float*)d_in[2];
    const float* bias   = (const float*)d_in[3];
    float* out = (float*)d_out;

    // ws layout: partials[8*128*8] f32 (32 KB) | cls bytes (512 KB)
    float* partials = (float*)d_ws;
    unsigned char* cls = (unsigned char*)d_ws + 32768;

    for (int k = 0; k <= N_; ++k) {                   // 9 pipelined launches
        const int napply = (k >= 1)  ? APPLY_BLOCKS_PER_IMG : 0;
        const int nstats = (k <= N_ - 1) ? STATS_BLOCKS_PER_IMG : 0;
        const int namax  = (k <= N_ - 1) ? AMAX_BLOCKS_PER_IMG  : 0;
        spade_fused<<<napply + nstats + namax, 256, 0, stream>>>(
            x, segmap, weight, bias, partials, cls, out,
            k - 1, k, napply, nstats);
    }
}